// Round 8
// baseline (482.299 us; speedup 1.0000x reference)
//
#include <hip/hip_runtime.h>
#include <hip/hip_bf16.h>

typedef unsigned short ushort_t;
typedef __attribute__((ext_vector_type(8))) short bf16x8;
typedef __attribute__((ext_vector_type(4))) float f32x4;
typedef __attribute__((ext_vector_type(16))) float f32x16;
typedef __attribute__((ext_vector_type(4))) int i32x4;
typedef __attribute__((ext_vector_type(2))) int i32x2;

#define MFMA32(A, B, C) __builtin_amdgcn_mfma_f32_32x32x16_bf16(A, B, C, 0, 0, 0)

#if defined(__has_builtin)
#if __has_builtin(__builtin_amdgcn_exp2f)
#define EXP2(x) __builtin_amdgcn_exp2f(x)
#else
#define EXP2(x) exp2f(x)
#endif
#else
#define EXP2(x) exp2f(x)
#endif

// Workgroup barrier WITHOUT vmcnt(0) drain: LDS producer/consumer visibility
// only (lgkmcnt). Global stores keep draining asynchronously.
#define LDS_BARRIER() asm volatile("s_waitcnt lgkmcnt(0)\n\ts_barrier" ::: "memory")

static constexpr int BATCH = 4;
static constexpr int DEP = 2048;
static constexpr int NH = 8;
static constexpr int CW = 128;   // per-head q/k/v width
static constexpr int HBn = 32;   // NH*BATCH
// log2(e)/sqrt(2048): folded into Q at projection so logits feed exp2 directly
static constexpr float QSCALE = (float)(1.4426950408889634 / 45.254833995939045);

static constexpr int PCOL = 520;  // P LDS row stride in ushorts (1040B, 16B-aligned)

static __device__ __forceinline__ ushort_t f2bf(float f) {
  __hip_bfloat16 h = __float2bfloat16(f);
  return __builtin_bit_cast(ushort_t, h);
}
static __device__ __forceinline__ float bf2f(unsigned int u) {
  unsigned int v = (u & 0xffffu) << 16;
  return __builtin_bit_cast(float, v);
}

// ---------------------------------------------------------------------------
// Kernel 1: pointwise QKV projection (Q pre-scaled by QSCALE). Unchanged.
//   q_ws/k_ws: bf16 [32 hb][2048 d][128 c];  vt_ws: bf16 [32 hb][128 c][2048 d]
// ---------------------------------------------------------------------------
__global__ __launch_bounds__(256) void proj_kernel(
    const float* __restrict__ feat,
    const float* __restrict__ Wq, const float* __restrict__ bq,
    const float* __restrict__ Wk, const float* __restrict__ bk,
    const float* __restrict__ Wv, const float* __restrict__ bv,
    ushort_t* __restrict__ q_ws, ushort_t* __restrict__ k_ws,
    ushort_t* __restrict__ vt_ws) {
  const int rt = blockIdx.x;
  const int iw = blockIdx.y >> 2;
  const int ct = blockIdx.y & 3;
  const float* W = (iw == 0) ? Wq : (iw == 1) ? Wk : Wv;
  const float* bs = (iw == 0) ? bq : (iw == 1) ? bk : bv;
  const int tid = threadIdx.x;

  __shared__ float fsm[32 * 64];
  __shared__ ushort_t re[32 * 256];

  {
    const float4* fg = reinterpret_cast<const float4*>(feat + (size_t)rt * 32 * 64);
    float4* fs = reinterpret_cast<float4*>(fsm);
    fs[tid] = fg[tid];
    fs[tid + 256] = fg[tid + 256];
  }
  __syncthreads();

  const int j = ct * 256 + tid;
  float acc[32];
  {
    const float b0 = bs[j];
#pragma unroll
    for (int r = 0; r < 32; ++r) acc[r] = b0;
  }
  for (int f4 = 0; f4 < 16; ++f4) {
    const float w0 = W[(f4 * 4 + 0) * 1024 + j];
    const float w1 = W[(f4 * 4 + 1) * 1024 + j];
    const float w2 = W[(f4 * 4 + 2) * 1024 + j];
    const float w3 = W[(f4 * 4 + 3) * 1024 + j];
#pragma unroll
    for (int r = 0; r < 32; ++r) {
      const float4 fv = *reinterpret_cast<const float4*>(&fsm[r * 64 + f4 * 4]);
      acc[r] = fmaf(fv.x, w0, acc[r]);
      acc[r] = fmaf(fv.y, w1, acc[r]);
      acc[r] = fmaf(fv.z, w2, acc[r]);
      acc[r] = fmaf(fv.w, w3, acc[r]);
    }
  }
  if (iw == 0) {
#pragma unroll
    for (int r = 0; r < 32; ++r) acc[r] *= QSCALE;
  }

  const int b = (rt * 32) >> 11;
  const int d0 = (rt * 32) & 2047;
  if (iw == 2) {
    const int h = j >> 7, cc = j & 127;
    ushort_t us[32];
#pragma unroll
    for (int r = 0; r < 32; ++r) us[r] = f2bf(acc[r]);
    ushort_t* dst = vt_ws + ((size_t)((h * BATCH + b) * CW + cc)) * DEP + d0;
#pragma unroll
    for (int i = 0; i < 4; ++i) {
      unsigned int a0 = us[8 * i + 0] | ((unsigned int)us[8 * i + 1] << 16);
      unsigned int a1 = us[8 * i + 2] | ((unsigned int)us[8 * i + 3] << 16);
      unsigned int a2 = us[8 * i + 4] | ((unsigned int)us[8 * i + 5] << 16);
      unsigned int a3 = us[8 * i + 6] | ((unsigned int)us[8 * i + 7] << 16);
      i32x4 v4 = {(int)a0, (int)a1, (int)a2, (int)a3};
      *reinterpret_cast<i32x4*>(dst + i * 8) = v4;
    }
  } else {
    ushort_t* wsb = (iw == 0) ? q_ws : k_ws;
#pragma unroll
    for (int r = 0; r < 32; ++r) re[r * 256 + tid] = f2bf(acc[r]);
    __syncthreads();
#pragma unroll
    for (int i = 0; i < 4; ++i) {
      const int id = tid + i * 256;
      const int r = id >> 5;
      const int c8 = (id & 31) * 8;
      const int jj = ct * 256 + c8;
      const int hh = jj >> 7, c2 = jj & 127;
      ushort_t* dst = wsb + ((size_t)((hh * BATCH + b) * DEP) + d0 + r) * CW + c2;
      *reinterpret_cast<i32x4*>(dst) = *reinterpret_cast<const i32x4*>(&re[r * 256 + c8]);
    }
  }
}

// ---------------------------------------------------------------------------
// Kernel 2: two-pass attention with sequential-drain attn writes.
// 2048 blocks (32 hb x 64 q-tiles of 32 rows), 256 threads (4 waves).
// Pass 1: QK^T + exp2 -> rowsums (wave w owns keys [w*512,+512)).
// Pass 2: 4 supersteps of 512 contiguous keys. Per inner step (128-key strip):
//   wave w computes QK tile at strip + w*32, stages normalized P (bf16) into
//   pbuf[32 q][520]; barrier; PV reads the full strip (b128 frags).
// After 4 steps: DRAIN -- each wave-store is 64 lanes x 16B = 1KB contiguous,
// 2KB sequential per attn row. This replaces the 128B-scatter writes that
// capped DRAM write efficiency at ~1.3 TB/s in R2-R7.
// ---------------------------------------------------------------------------
__global__ __launch_bounds__(256, 4) void attn_kernel(
    const ushort_t* __restrict__ q_ws, const ushort_t* __restrict__ k_ws,
    const ushort_t* __restrict__ vt_ws, float* __restrict__ out,
    float* __restrict__ attn) {
  __shared__ ushort_t pbuf[32 * PCOL];  // [q][key-in-superstep], 33.3 KB
  __shared__ float rsbuf[4][32];
  __shared__ float invbuf[32];

  // XCD swizzle: per XCD, blocks of one hb run back-to-back (L2 locality)
  const int bid0 = blockIdx.x;
  const int wg = (bid0 & 7) * 256 + (bid0 >> 3);
  const int hb = wg >> 6;
  const int qbase = (wg & 63) * 32;

  const int tid = threadIdx.x;
  const int w = tid >> 6, l = tid & 63;
  const int q = l & 31, h = l >> 5;

  // Q B-fragments: lane holds Q[f = fs*16 + h*8 + j][qbase+q]
  bf16x8 qf[8];
  {
    const ushort_t* qrow = q_ws + ((size_t)(hb * DEP + qbase + q)) * CW + h * 8;
#pragma unroll
    for (int fs = 0; fs < 8; ++fs)
      qf[fs] = *reinterpret_cast<const bf16x8*>(qrow + fs * 16);
  }

  // ---- pass 1: row sums (wave w covers keys [w*512, w*512+512)) ----
  {
    const ushort_t* kb1 = k_ws + (size_t)hb * DEP * CW +
                          (size_t)(w * 512 + q) * CW + h * 8;
    float rs = 0.f;
    for (int t = 0; t < 16; ++t) {
      const ushort_t* krow = kb1 + (size_t)(t * 32) * CW;
      bf16x8 ka[8];
#pragma unroll
      for (int fs = 0; fs < 8; ++fs)
        ka[fs] = *reinterpret_cast<const bf16x8*>(krow + fs * 16);
      f32x16 s = {};
#pragma unroll
      for (int fs = 0; fs < 8; ++fs) s = MFMA32(ka[fs], qf[fs], s);
#pragma unroll
      for (int r = 0; r < 16; ++r) rs += EXP2(s[r]);
    }
    rs += __shfl_xor(rs, 32);
    if (h == 0) rsbuf[w][q] = rs;
  }
  __syncthreads();
  if (tid < 32)
    invbuf[tid] =
        1.f / ((rsbuf[0][tid] + rsbuf[1][tid]) + (rsbuf[2][tid] + rsbuf[3][tid]));
  __syncthreads();
  const float invq = invbuf[q];

  // ---- pass 2 ----
  const ushort_t* kb2 = k_ws + (size_t)hb * DEP * CW + (size_t)q * CW + h * 8;
  const ushort_t* vb = vt_ws + ((size_t)(hb * CW + w * 32 + q)) * DEP + h * 8;
  float* attnbase = attn + (size_t)hb * DEP * DEP + (size_t)qbase * DEP;

  f32x16 accO = {};
  for (int T = 0; T < 4; ++T) {
#pragma unroll
    for (int s = 0; s < 4; ++s) {
      // STAGE: QK tile at keys T*512 + s*128 + w*32 .. +32, normalized -> pbuf
      {
        const int tile = T * 512 + s * 128 + w * 32;
        const ushort_t* krow = kb2 + (size_t)tile * CW;
        bf16x8 ka[8];
#pragma unroll
        for (int fs = 0; fs < 8; ++fs)
          ka[fs] = *reinterpret_cast<const bf16x8*>(krow + fs * 16);
        f32x16 sv = {};
#pragma unroll
        for (int fs = 0; fs < 8; ++fs) sv = MFMA32(ka[fs], qf[fs], sv);
        // sv[r] = S[key = tile + (r&3)+8*(r>>2)+4h][q]
        ushort_t* tb = &pbuf[q * PCOL + s * 128 + w * 32 + 4 * h];
#pragma unroll
        for (int i2 = 0; i2 < 4; ++i2) {
          const float p0 = EXP2(sv[4 * i2 + 0]) * invq;
          const float p1 = EXP2(sv[4 * i2 + 1]) * invq;
          const float p2 = EXP2(sv[4 * i2 + 2]) * invq;
          const float p3 = EXP2(sv[4 * i2 + 3]) * invq;
          const unsigned int pk0 =
              (unsigned int)f2bf(p0) | ((unsigned int)f2bf(p1) << 16);
          const unsigned int pk1 =
              (unsigned int)f2bf(p2) | ((unsigned int)f2bf(p3) << 16);
          i32x2 pw = {(int)pk0, (int)pk1};
          *reinterpret_cast<i32x2*>(tb + 8 * i2) = pw;
        }
      }
      LDS_BARRIER();
      // PV over the contiguous 128-key strip (all 4 waves' tiles)
      {
        const ushort_t* vs = vb + T * 512 + s * 128;
        const ushort_t* pb = &pbuf[q * PCOL + s * 128 + 8 * h];
#pragma unroll
        for (int kh = 0; kh < 8; ++kh) {
          bf16x8 pbv = *reinterpret_cast<const bf16x8*>(pb + kh * 16);
          bf16x8 va = *reinterpret_cast<const bf16x8*>(vs + kh * 16);
          accO = MFMA32(va, pbv, accO);
        }
      }
      // no barrier here: next STAGE writes strip s+1 (disjoint); superstep
      // boundary WAR handled by the post-drain barrier below.
    }
    // DRAIN: attn rows qbase+w*8 .. +8, cols [T*512, T*512+512).
    // Each store: 64 lanes x 16B = 1KB contiguous; 2 per row.
    {
#pragma unroll
      for (int j = 0; j < 8; ++j) {
        const int r = w * 8 + j;
        float* arow = attnbase + (size_t)r * DEP + T * 512;
        const ushort_t* prow = &pbuf[r * PCOL];
#pragma unroll
        for (int half = 0; half < 2; ++half) {
          const int col = half * 256 + l * 4;
          const i32x2 pr = *reinterpret_cast<const i32x2*>(prow + col);
          f32x4 v;
          v[0] = bf2f((unsigned int)pr[0]);
          v[1] = bf2f(((unsigned int)pr[0]) >> 16);
          v[2] = bf2f((unsigned int)pr[1]);
          v[3] = bf2f(((unsigned int)pr[1]) >> 16);
          *reinterpret_cast<f32x4*>(arow + col) = v;
        }
      }
    }
    LDS_BARRIER();  // WAR: drain reads complete before next superstep's STAGE
  }

  // ---- out store: lane owns col q, c-slice [w*32, w*32+32) ----
  {
    const int hh = hb >> 2, b = hb & 3;
#pragma unroll
    for (int r = 0; r < 16; ++r) {
      const int c = w * 32 + (r & 3) + 8 * (r >> 2) + 4 * h;
      out[((size_t)(b * 16 + hh * 2 + (c >> 6)) * DEP + qbase + q) * 64 + (c & 63)] =
          accO[r];
    }
  }
}

extern "C" void kernel_launch(void* const* d_in, const int* in_sizes, int n_in,
                              void* d_out, int out_size, void* d_ws, size_t ws_size,
                              hipStream_t stream) {
  const float* feat = (const float*)d_in[0];
  const float* Wq = (const float*)d_in[1];
  const float* bq = (const float*)d_in[2];
  const float* Wk = (const float*)d_in[3];
  const float* bk = (const float*)d_in[4];
  const float* Wv = (const float*)d_in[5];
  const float* bv = (const float*)d_in[6];

  ushort_t* q_ws = (ushort_t*)d_ws;
  ushort_t* k_ws = q_ws + (size_t)HBn * DEP * CW;
  ushort_t* vt_ws = k_ws + (size_t)HBn * DEP * CW;

  float* out = (float*)d_out;
  float* attn = out + (size_t)BATCH * 16 * DEP * 64;

  hipLaunchKernelGGL(proj_kernel, dim3(256, 12), dim3(256), 0, stream,
                     feat, Wq, bq, Wk, bk, Wv, bv, q_ws, k_ws, vt_ws);
  hipLaunchKernelGGL(attn_kernel, dim3(2048), dim3(256), 0, stream,
                     q_ws, k_ws, vt_ws, out, attn);
}

// Round 9
// 314.514 us; speedup vs baseline: 1.5335x; 1.5335x over previous
//
#include <hip/hip_runtime.h>
#include <hip/hip_bf16.h>

typedef unsigned short ushort_t;
typedef __attribute__((ext_vector_type(8))) short bf16x8;
typedef __attribute__((ext_vector_type(4))) float f32x4;
typedef __attribute__((ext_vector_type(16))) float f32x16;
typedef __attribute__((ext_vector_type(4))) int i32x4;
typedef __attribute__((ext_vector_type(2))) int i32x2;

#define MFMA32(A, B, C) __builtin_amdgcn_mfma_f32_32x32x16_bf16(A, B, C, 0, 0, 0)

#if defined(__has_builtin)
#if __has_builtin(__builtin_amdgcn_exp2f)
#define EXP2(x) __builtin_amdgcn_exp2f(x)
#else
#define EXP2(x) exp2f(x)
#endif
#else
#define EXP2(x) exp2f(x)
#endif

// LDS-only barrier (no vmcnt drain): global stores keep draining async.
#define LDS_BARRIER() asm volatile("s_waitcnt lgkmcnt(0)\n\ts_barrier" ::: "memory")

static constexpr int BATCH = 4;
static constexpr int DEP = 2048;
static constexpr int CW = 128;   // per-head q/k/v width
static constexpr int HBn = 32;   // NH*BATCH
// log2(e)/sqrt(2048): folded into Q at projection so logits feed exp2 directly
static constexpr float QSCALE = (float)(1.4426950408889634 / 45.254833995939045);

static constexpr int PCOL = 264;  // P LDS row stride (ushorts); 528B: 16B-aligned

static __device__ __forceinline__ ushort_t f2bf(float f) {
  __hip_bfloat16 h = __float2bfloat16(f);
  return __builtin_bit_cast(ushort_t, h);
}
static __device__ __forceinline__ float bf2f(unsigned int u) {
  unsigned int v = (u & 0xffffu) << 16;
  return __builtin_bit_cast(float, v);
}

// ---------------------------------------------------------------------------
// Kernel 1: QKV projection. Q -> [hb][d][c] (as before, pre-scaled).
// K -> fragment-linear kf[hb][tile(64)][fs(8)][lane(64)][8]:
//      element K[tile*32+q][fs*16+h*8+j] at lane = h*32+q  -> attn QK loads
//      become base + lane*16B (1KB contiguous per instruction).
// V -> fragment-linear vf[hb][tile(64)][khalf(2)][w(4)][lane(64)][8]:
//      element V^T[w*32+q][tile*32+khalf*16+h*8+j] at lane = h*32+q.
// ---------------------------------------------------------------------------
__global__ __launch_bounds__(256) void proj_kernel(
    const float* __restrict__ feat,
    const float* __restrict__ Wq, const float* __restrict__ bq,
    const float* __restrict__ Wk, const float* __restrict__ bk,
    const float* __restrict__ Wv, const float* __restrict__ bv,
    ushort_t* __restrict__ q_ws, ushort_t* __restrict__ kf,
    ushort_t* __restrict__ vf) {
  const int rt = blockIdx.x;
  const int iw = blockIdx.y >> 2;
  const int ct = blockIdx.y & 3;
  const float* W = (iw == 0) ? Wq : (iw == 1) ? Wk : Wv;
  const float* bs = (iw == 0) ? bq : (iw == 1) ? bk : bv;
  const int tid = threadIdx.x;

  __shared__ float fsm[32 * 64];
  __shared__ ushort_t re[32 * 264];  // repack buffer, stride 264 (16B-aligned rows)

  {
    const float4* fg = reinterpret_cast<const float4*>(feat + (size_t)rt * 32 * 64);
    float4* fs = reinterpret_cast<float4*>(fsm);
    fs[tid] = fg[tid];
    fs[tid + 256] = fg[tid + 256];
  }
  __syncthreads();

  const int j = ct * 256 + tid;
  float acc[32];
  {
    const float b0 = bs[j];
#pragma unroll
    for (int r = 0; r < 32; ++r) acc[r] = b0;
  }
  for (int f4 = 0; f4 < 16; ++f4) {
    const float w0 = W[(f4 * 4 + 0) * 1024 + j];
    const float w1 = W[(f4 * 4 + 1) * 1024 + j];
    const float w2 = W[(f4 * 4 + 2) * 1024 + j];
    const float w3 = W[(f4 * 4 + 3) * 1024 + j];
#pragma unroll
    for (int r = 0; r < 32; ++r) {
      const float4 fv = *reinterpret_cast<const float4*>(&fsm[r * 64 + f4 * 4]);
      acc[r] = fmaf(fv.x, w0, acc[r]);
      acc[r] = fmaf(fv.y, w1, acc[r]);
      acc[r] = fmaf(fv.z, w2, acc[r]);
      acc[r] = fmaf(fv.w, w3, acc[r]);
    }
  }
  if (iw == 0) {
#pragma unroll
    for (int r = 0; r < 32; ++r) acc[r] *= QSCALE;
  }

  const int b = (rt * 32) >> 11;
  const int d0 = (rt * 32) & 2047;
  const int tile = d0 >> 5;

  if (iw == 2) {
    // V fragment-linear: thread owns column cc of head hd, keys d0..d0+31.
    const int hd = j >> 7, cc = j & 127;
    const int hbv = hd * BATCH + b;
    ushort_t us[32];
#pragma unroll
    for (int r = 0; r < 32; ++r) us[r] = f2bf(acc[r]);
    ushort_t* dst =
        vf + (((size_t)(hbv * 64 + tile) * 2 * 4 + (cc >> 5)) * 64 + (cc & 31)) * 8;
#pragma unroll
    for (int khalf = 0; khalf < 2; ++khalf)
#pragma unroll
      for (int ksub = 0; ksub < 2; ++ksub) {
        const int r0 = khalf * 16 + ksub * 8;
        unsigned int a0 = us[r0 + 0] | ((unsigned int)us[r0 + 1] << 16);
        unsigned int a1 = us[r0 + 2] | ((unsigned int)us[r0 + 3] << 16);
        unsigned int a2 = us[r0 + 4] | ((unsigned int)us[r0 + 5] << 16);
        unsigned int a3 = us[r0 + 6] | ((unsigned int)us[r0 + 7] << 16);
        i32x4 v4 = {(int)a0, (int)a1, (int)a2, (int)a3};
        *reinterpret_cast<i32x4*>(dst + khalf * 2048 + ksub * 256) = v4;
      }
  } else if (iw == 1) {
    // K fragment-linear via LDS repack; stores are 1KB-contiguous per wave.
#pragma unroll
    for (int r = 0; r < 32; ++r) re[r * 264 + tid] = f2bf(acc[r]);
    __syncthreads();
#pragma unroll
    for (int i = 0; i < 4; ++i) {
      const int id = tid + i * 256;
      const int fs_loc = id >> 6;      // 0..15 (f-chunk within this ct quarter)
      const int h2 = (id >> 5) & 1;
      const int r = id & 31;
      i32x4 val = *reinterpret_cast<const i32x4*>(&re[r * 264 + fs_loc * 16 + h2 * 8]);
      const int hh2 = ct * 2 + (fs_loc >> 3);
      const int hbk = hh2 * BATCH + b;
      ushort_t* dst = kf + ((size_t)(hbk * 64 + tile) * 8 + (fs_loc & 7)) * 512 +
                      h2 * 256 + r * 8;
      *reinterpret_cast<i32x4*>(dst) = val;
    }
  } else {
    // Q: [hb][d][c] (fragments gathered once per attn block; scatter OK)
#pragma unroll
    for (int r = 0; r < 32; ++r) re[r * 264 + tid] = f2bf(acc[r]);
    __syncthreads();
#pragma unroll
    for (int i = 0; i < 4; ++i) {
      const int id = tid + i * 256;
      const int r = id >> 5;
      const int c8 = (id & 31) * 8;
      const int jj = ct * 256 + c8;
      const int hh = jj >> 7, c2 = jj & 127;
      ushort_t* dst = q_ws + ((size_t)((hh * BATCH + b) * DEP) + d0 + r) * CW + c2;
      *reinterpret_cast<i32x4*>(dst) = *reinterpret_cast<const i32x4*>(&re[r * 264 + c8]);
    }
  }
}

// ---------------------------------------------------------------------------
// Kernel 2: two-pass attention, ALL K/V loads 1KB-coalesced from fragment-
// linear layouts (no LDS staging of K/V). 2048 blocks (32 hb x 64 q-tiles),
// 256 threads (4 waves). Pass 1: rowsums, 2-deep register prefetch.
// Pass 2: 8 supersteps of 256 keys; per 128-key strip each wave computes its
// 32-key QK tile, stages normalized P (bf16) -> pbuf; barrier; PV reads all
// 128 keys (LDS P-frags + coalesced V-frags). Drain: 1KB sequential attn
// stores per instruction. lgkm-only barriers throughout.
// ---------------------------------------------------------------------------
__global__ __launch_bounds__(256, 3) void attn_kernel(
    const ushort_t* __restrict__ q_ws, const ushort_t* __restrict__ kf,
    const ushort_t* __restrict__ vf, float* __restrict__ out,
    float* __restrict__ attn) {
  __shared__ ushort_t pbuf[32 * PCOL];
  __shared__ float rsbuf[4][32];
  __shared__ float invbuf[32];

  // XCD swizzle: per XCD, blocks of one hb run back-to-back (L2 locality)
  const int bid0 = blockIdx.x;
  const int wg = (bid0 & 7) * 256 + (bid0 >> 3);
  const int hb = wg >> 6;
  const int qbase = (wg & 63) * 32;

  const int tid = threadIdx.x;
  const int w = tid >> 6, l = tid & 63;
  const int q = l & 31, h = l >> 5;

  // Q B-fragments (one-time scattered gather)
  bf16x8 qf[8];
  {
    const ushort_t* qrow = q_ws + ((size_t)(hb * DEP + qbase + q)) * CW + h * 8;
#pragma unroll
    for (int fs = 0; fs < 8; ++fs)
      qf[fs] = *reinterpret_cast<const bf16x8*>(qrow + fs * 16);
  }

  const ushort_t* kfb = kf + (size_t)hb * 64 * 4096 + l * 8;
  const ushort_t* vfb = vf + (size_t)hb * 64 * 4096 + l * 8;

  // ---- pass 1: row sums, wave w owns tiles {w, 4+w, ..., 60+w} ----
  float rs = 0.f;
  {
    bf16x8 kaA[8], kaB[8];
#define LOADK(KA, T_)                                                        \
  {                                                                          \
    const ushort_t* p_ = kfb + (size_t)((T_)*4 + w) * 4096;                  \
    _Pragma("unroll") for (int fs = 0; fs < 8; ++fs) KA[fs] =                \
        *reinterpret_cast<const bf16x8*>(p_ + fs * 512);                     \
  }
#define DOTACC(KA)                                                           \
  {                                                                          \
    f32x16 s_ = {};                                                          \
    _Pragma("unroll") for (int fs = 0; fs < 8; ++fs) s_ =                    \
        MFMA32(KA[fs], qf[fs], s_);                                          \
    _Pragma("unroll") for (int r = 0; r < 16; ++r) rs += EXP2(s_[r]);        \
  }
    LOADK(kaA, 0);
#pragma unroll
    for (int t = 0; t < 16; t += 2) {
      LOADK(kaB, t + 1);
      DOTACC(kaA);
      if (t + 2 < 16) LOADK(kaA, t + 2);
      DOTACC(kaB);
    }
#undef LOADK
#undef DOTACC
  }
  rs += __shfl_xor(rs, 32);
  if (h == 0) rsbuf[w][q] = rs;
  __syncthreads();
  if (tid < 32)
    invbuf[tid] =
        1.f / ((rsbuf[0][tid] + rsbuf[1][tid]) + (rsbuf[2][tid] + rsbuf[3][tid]));
  __syncthreads();
  const float invq = invbuf[q];

  // ---- pass 2 ----
  f32x16 accO = {};
  float* attnbase = attn + (size_t)hb * DEP * DEP + (size_t)qbase * DEP;

  for (int T = 0; T < 8; ++T) {
#pragma unroll
    for (int s = 0; s < 2; ++s) {
      const int kt = T * 8 + s * 4 + w;
      // STAGE: QK tile (coalesced frag loads) -> normalized P -> pbuf
      {
        const ushort_t* p = kfb + (size_t)kt * 4096;
        bf16x8 ka[8];
#pragma unroll
        for (int fs = 0; fs < 8; ++fs)
          ka[fs] = *reinterpret_cast<const bf16x8*>(p + fs * 512);
        f32x16 sv = {};
#pragma unroll
        for (int fs = 0; fs < 8; ++fs) sv = MFMA32(ka[fs], qf[fs], sv);
        // sv[r] = S[key = kt*32 + (r&3)+8*(r>>2)+4h][q]
        ushort_t* tb = pbuf + q * PCOL + s * 128 + w * 32 + 4 * h;
#pragma unroll
        for (int i2 = 0; i2 < 4; ++i2) {
          const float p0 = EXP2(sv[4 * i2 + 0]) * invq;
          const float p1 = EXP2(sv[4 * i2 + 1]) * invq;
          const float p2 = EXP2(sv[4 * i2 + 2]) * invq;
          const float p3 = EXP2(sv[4 * i2 + 3]) * invq;
          const unsigned int pk0 =
              (unsigned int)f2bf(p0) | ((unsigned int)f2bf(p1) << 16);
          const unsigned int pk1 =
              (unsigned int)f2bf(p2) | ((unsigned int)f2bf(p3) << 16);
          i32x2 pw = {(int)pk0, (int)pk1};
          *reinterpret_cast<i32x2*>(tb + 8 * i2) = pw;
        }
      }
      LDS_BARRIER();
      // PV over the strip (LDS P-frags + coalesced V-frags)
      {
        const ushort_t* pb = pbuf + q * PCOL + s * 128 + 8 * h;
#pragma unroll
        for (int kh = 0; kh < 8; ++kh) {
          bf16x8 pbv = *reinterpret_cast<const bf16x8*>(pb + kh * 16);
          const ushort_t* vaddr =
              vfb + (size_t)(((T * 8 + s * 4 + (kh >> 1)) * 2 + (kh & 1)) * 4 + w) * 512;
          bf16x8 va = *reinterpret_cast<const bf16x8*>(vaddr);
          accO = MFMA32(va, pbv, accO);
        }
      }
    }
    // DRAIN: rows qbase+w*8..+8, cols [T*256, T*256+256); 1KB/instruction
    {
#pragma unroll
      for (int jr = 0; jr < 8; ++jr) {
        const int r = w * 8 + jr;
        const i32x2 pr = *reinterpret_cast<const i32x2*>(pbuf + r * PCOL + l * 4);
        f32x4 v;
        v[0] = bf2f((unsigned int)pr[0]);
        v[1] = bf2f(((unsigned int)pr[0]) >> 16);
        v[2] = bf2f((unsigned int)pr[1]);
        v[3] = bf2f(((unsigned int)pr[1]) >> 16);
        *reinterpret_cast<f32x4*>(attnbase + (size_t)r * DEP + T * 256 + l * 4) = v;
      }
    }
    LDS_BARRIER();  // WAR before next superstep overwrites pbuf
  }

  // ---- out store: lane owns col q, c-slice [w*32, w*32+32) ----
  {
    const int hh = hb >> 2, b = hb & 3;
#pragma unroll
    for (int r = 0; r < 16; ++r) {
      const int c = w * 32 + (r & 3) + 8 * (r >> 2) + 4 * h;
      out[((size_t)(b * 16 + hh * 2 + (c >> 6)) * DEP + qbase + q) * 64 + (c & 63)] =
          accO[r];
    }
  }
}

extern "C" void kernel_launch(void* const* d_in, const int* in_sizes, int n_in,
                              void* d_out, int out_size, void* d_ws, size_t ws_size,
                              hipStream_t stream) {
  const float* feat = (const float*)d_in[0];
  const float* Wq = (const float*)d_in[1];
  const float* bq = (const float*)d_in[2];
  const float* Wk = (const float*)d_in[3];
  const float* bk = (const float*)d_in[4];
  const float* Wv = (const float*)d_in[5];
  const float* bv = (const float*)d_in[6];

  ushort_t* q_ws = (ushort_t*)d_ws;
  ushort_t* kf = q_ws + (size_t)HBn * DEP * CW;
  ushort_t* vf = kf + (size_t)HBn * DEP * CW;

  float* out = (float*)d_out;
  float* attn = out + (size_t)BATCH * 16 * DEP * 64;

  hipLaunchKernelGGL(proj_kernel, dim3(256, 12), dim3(256), 0, stream,
                     feat, Wq, bq, Wk, bk, Wv, bv, q_ws, kf, vf);
  hipLaunchKernelGGL(attn_kernel, dim3(2048), dim3(256), 0, stream,
                     q_ws, kf, vf, out, attn);
}